// Round 7
// baseline (419.457 us; speedup 1.0000x reference)
//
#include <hip/hip_runtime.h>
#include <hip/hip_bf16.h>

// B=16, SEQ=512, NF=32, E=128, HID=512, PRED=96, N_FFT=64, HOP=32, TOPM=32
// W=17, F=33, LAM=0.01
#define LAM 0.01f

typedef __attribute__((ext_vector_type(8))) short v8s;
typedef __attribute__((ext_vector_type(4))) float v4f;

static __device__ __forceinline__ unsigned short f2bf(float f) {
    union { float f; unsigned int u; } v; v.f = f;
    unsigned int u = v.u;
    u += 0x7fffu + ((u >> 16) & 1u);   // RNE
    return (unsigned short)(u >> 16);
}
static __device__ __forceinline__ float bf2f(unsigned short h) {
    union { unsigned int u; float f; } c; c.u = ((unsigned int)h) << 16;
    return c.f;
}

// async global->LDS DMA, 16 B/lane; lds base wave-uniform, lane i -> base+16i
static __device__ __forceinline__ void async16(const void* g, void* l) {
    __builtin_amdgcn_global_load_lds(
        (const __attribute__((address_space(1))) unsigned int*)g,
        (__attribute__((address_space(3))) unsigned int*)l, 16, 0, 0);
}

// Workspace layout (bytes)
#define OFF_COEF 0ull
#define OFF_V    69632ull
#define OFF_BINS 2297856ull
#define OFF_AIMG 3411968ull                     // 512*65536 bf16 swizzled = 67,108,864
#define OFF_W1P  70520832ull                    // 65536*512 bf16 swizzled = 67,108,864
#define OFF_HP   137629696ull                   // KS*512*512*2 (bf16 partials)

// ---------------------------------------------------------------------------
// Kernel A: coef[w][e][j]: j=0..5 -> emb . Wj[w,:,e]; j=6 -> br-LAM; j=7 -> bi-LAM
// ---------------------------------------------------------------------------
__global__ __launch_bounds__(128) void coef_kernel(
    const float* __restrict__ emb,
    const float* __restrict__ Wr, const float* __restrict__ Wi,
    const float* __restrict__ Wrl, const float* __restrict__ Wil,
    const float* __restrict__ Wrr, const float* __restrict__ Wir,
    const float* __restrict__ br, const float* __restrict__ bi,
    float* __restrict__ coef)
{
    int w = blockIdx.x, j = blockIdx.y, e = threadIdx.x;
    float out;
    if (j < 6) {
        const float* Wj;
        switch (j) {
            case 0: Wj = Wr; break; case 1: Wj = Wi; break;
            case 2: Wj = Wrl; break; case 3: Wj = Wil; break;
            case 4: Wj = Wrr; break; default: Wj = Wir; break;
        }
        const float* p = Wj + (size_t)w * 16384 + e;
        float acc = 0.f;
        #pragma unroll 8
        for (int ep = 0; ep < 128; ++ep) acc = fmaf(emb[ep], p[ep * 128], acc);
        out = acc;
    } else if (j == 6) {
        out = br[w * 128 + e] - LAM;
    } else {
        out = bi[w * 128 + e] - LAM;
    }
    coef[((size_t)(w * 128 + e)) * 8 + j] = out;
}

// ---------------------------------------------------------------------------
// Kernel B: per (b,n): windowed 64-pt DFT, 17x33 bins, rank |S|, store top-32.
// ---------------------------------------------------------------------------
__global__ __launch_bounds__(256) void stft_kernel(
    const float* __restrict__ x, float2* __restrict__ V, int* __restrict__ bins)
{
    __shared__ float sig[576];
    __shared__ float winT[64];
    __shared__ float2 tw[64];
    __shared__ float2 Sbuf[17 * 33];
    __shared__ float absb[17 * 33];

    const int blk = blockIdx.x;
    const int b = blk >> 5, n = blk & 31;
    const int tid = threadIdx.x;
    const float C64 = 0.09817477042468103f; // 2*pi/64

    if (tid < 64) {
        float ang = (float)tid * C64;
        winT[tid] = 0.5f - 0.5f * cosf(ang);
        tw[tid] = make_float2(cosf(ang), sinf(ang));   // accurate libm: top-k tie safety
    }
    for (int l = tid; l < 576; l += 256) {
        int t = (l < 32) ? (32 - l) : ((l < 544) ? (l - 32) : (1054 - l)); // reflect
        sig[l] = x[(size_t)b * 16384 + t * 32 + n];
    }
    __syncthreads();

    for (int task = tid; task < 561; task += 256) {
        int w = task / 33, f = task - w * 33;
        float sr = 0.f, si = 0.f;
        int base = w * 32;
        for (int t = 0; t < 64; ++t) {
            float sw = sig[base + t] * winT[t];
            float2 cs = tw[(f * t) & 63];
            sr = fmaf(sw, cs.x, sr);
            si = fmaf(sw, -cs.y, si);
        }
        Sbuf[task] = make_float2(sr, si);
        absb[task] = sqrtf(fmaf(sr, sr, si * si));
    }
    __syncthreads();

    for (int task = tid; task < 561; task += 256) {
        int w = task / 33, f = task - w * 33;
        float a = absb[task];
        int base = w * 33, rank = 0;
        for (int j = 0; j < 33; ++j) {
            float aj = absb[base + j];
            rank += (aj > a) || (aj == a && j < f);   // stable
        }
        if (rank < 32) {
            size_t o = ((size_t)blk * 17 + w) * 32 + rank;
            V[o] = Sbuf[task];
            bins[o] = f;
        }
    }
}

// ---------------------------------------------------------------------------
// Kernel W-cvt: w1 f32 -> bf16 swizzled DMA image.
// Image: [nt(4)][kb(2048)][n'(128)][32k]; chunk c_log at pos c_log^((n'>>2)&3).
// ---------------------------------------------------------------------------
__global__ __launch_bounds__(256) void cvt_kernel(
    const float* __restrict__ w1, unsigned short* __restrict__ w1p)
{
    __shared__ float T[32][132];
    const int kb = blockIdx.x, nt = blockIdx.y;
    const int tid = threadIdx.x;

    #pragma unroll
    for (int p = 0; p < 4; ++p) {
        int r = (tid >> 5) + p * 8;
        int c = (tid & 31) * 4;
        float4 v = *(const float4*)&w1[((size_t)(kb * 32 + r)) * 512 + nt * 128 + c];
        T[r][c] = v.x; T[r][c + 1] = v.y; T[r][c + 2] = v.z; T[r][c + 3] = v.w;
    }
    __syncthreads();

    unsigned short* dst = w1p + ((size_t)nt * 2048 + kb) * 4096;
    #pragma unroll
    for (int p = 0; p < 2; ++p) {
        int pos = tid + 256 * p;            // 16-B chunk index
        int np = pos >> 2, cs = pos & 3;
        int clog = cs ^ ((np >> 2) & 3);
        unsigned int pk[4];
        #pragma unroll
        for (int j2 = 0; j2 < 4; ++j2) {
            unsigned short lo = f2bf(T[clog * 8 + j2 * 2][np]);
            unsigned short hi = f2bf(T[clog * 8 + j2 * 2 + 1][np]);
            pk[j2] = (unsigned int)lo | ((unsigned int)hi << 16);
        }
        *(uint4*)&dst[pos * 8] = make_uint4(pk[0], pk[1], pk[2], pk[3]);
    }
}

// ---------------------------------------------------------------------------
// Kernel C: mid — restructured (R7):
//  * B-fragment (Y) computed per-lane IN REGISTERS (no Yt LDS stage).
//  * M1 (A-operand, shared by all 4 waves) double-buffered in LDS ->
//    exactly ONE barrier per w-iteration.
//  * V stored SoA (Vre/Vim) for packed-f32 m-pair math.
//  * w-split grid 1024: half h does w in [8h, 8h+8], flushes rows [256h,+256).
// ---------------------------------------------------------------------------
#define MID_ROLL(J0, J1, J2, J3)                                                \
    {                                                                           \
        _Pragma("unroll") for (int e2 = 0; e2 < 2; ++e2)                        \
        _Pragma("unroll") for (int i = 0; i < 4; ++i) {                         \
            roll[e2][J0][i] = fmaf(acc[0][e2][i], win16[0][i], roll[e2][J0][i]);\
            roll[e2][J1][i] = fmaf(acc[1][e2][i], win16[1][i], roll[e2][J1][i]);\
            roll[e2][J2][i] = fmaf(acc[2][e2][i], win16[2][i], roll[e2][J2][i]);\
            roll[e2][J3][i] = fmaf(acc[3][e2][i], win16[3][i], roll[e2][J3][i]);\
        }                                                                       \
    }

#define MID_FLUSH(JJA, JJB)                                                     \
    {                                                                           \
        _Pragma("unroll") for (int i = 0; i < 4; ++i) {                         \
            int tp = 32 * (w - 1) + q * 4 + i;                                  \
            float xb = xs[tp];                                                  \
            _Pragma("unroll") for (int e2 = 0; e2 < 2; ++e2) {                  \
                float val = fmaf(roll[e2][JJA][i], renv[0][i], xb * emb2[e2]);  \
                Aimg[cbase[e2] + (size_t)tp * 16384] = f2bf(val);               \
                roll[e2][JJA][i] = 0.f;                                         \
            }                                                                   \
            int tp2 = tp + 16;                                                  \
            float xb2 = xs[tp2];                                                \
            _Pragma("unroll") for (int e2 = 0; e2 < 2; ++e2) {                  \
                float val = fmaf(roll[e2][JJB][i], renv[1][i], xb2 * emb2[e2]); \
                Aimg[cbase[e2] + (size_t)tp2 * 16384] = f2bf(val);              \
                roll[e2][JJB][i] = 0.f;                                         \
            }                                                                   \
        }                                                                       \
    }

__global__ __launch_bounds__(256, 3) void mid_kernel(
    const float* __restrict__ x, const float* __restrict__ emb,
    const float* __restrict__ coef, const float2* __restrict__ V,
    const int* __restrict__ bins, unsigned short* __restrict__ Aimg)
{
    __shared__ unsigned short M1t[2][64 * 72];     // double-buffered A-operand
    __shared__ float cosT[64];
    __shared__ float sinT[64];
    __shared__ __align__(16) float Vre[17 * 32];
    __shared__ __align__(16) float Vim[17 * 32];
    __shared__ int Bns[17 * 32];
    __shared__ float xs[512];

    const int blk2 = blockIdx.x;
    const int blk = blk2 & 511;          // (b,n)
    const int wbeg = (blk2 >> 9) * 8;    // 0 or 8
    const int b = blk >> 5, n = blk & 31;
    const int tid = threadIdx.x;
    const int wave = tid >> 6, lane = tid & 63, l15 = lane & 15, q = lane >> 4;
    const float C64 = 0.09817477042468103f;

    if (tid < 64) {
        float ang = (float)tid * C64;
        cosT[tid] = __cosf(ang);
        sinT[tid] = __sinf(ang);
    }
    {
        const float2* Vg = V + (size_t)blk * 544;
        const int* Bg = bins + (size_t)blk * 544;
        for (int i = tid; i < 544; i += 256) {
            float2 v = Vg[i];
            Vre[i] = v.x; Vim[i] = v.y;
            Bns[i] = Bg[i];
        }
        for (int i = tid; i < 512; i += 256) xs[i] = x[(size_t)b * 16384 + i * 32 + n];
    }

    float win16[4][4];
    #pragma unroll
    for (int tt = 0; tt < 4; ++tt)
        #pragma unroll
        for (int i = 0; i < 4; ++i) {
            int t = tt * 16 + q * 4 + i;
            win16[tt][i] = 0.5f - 0.5f * __cosf((float)t * C64);
        }
    float renv[2][4];
    #pragma unroll
    for (int hf = 0; hf < 2; ++hf)
        #pragma unroll
        for (int i = 0; i < 4; ++i) {
            int k = hf * 16 + q * 4 + i;
            float w0 = 0.5f - 0.5f * __cosf((float)k * C64);
            float w1v = 0.5f - 0.5f * __cosf((float)(k + 32) * C64);
            renv[hf][i] = 1.0f / (w0 * w0 + w1v * w1v);
        }
    int ebase[2];
    float emb2[2];
    size_t cbase[2];
    const int mt = blk >> 7, mp = blk & 127, s = (mp >> 2) & 3;
    #pragma unroll
    for (int e2 = 0; e2 < 2; ++e2) {
        ebase[e2] = (wave * 2 + e2) * 16 + l15;
        emb2[e2] = emb[ebase[e2]];
        int e = ebase[e2];
        int echunk = e >> 5, clog = (e >> 3) & 3, cs = clog ^ s, el = e & 7;
        cbase[e2] = ((size_t)mt * 2048 + echunk) * 4096 + mp * 32 + cs * 8 + el;
    }

    float roll[2][4][4];
    #pragma unroll
    for (int e2 = 0; e2 < 2; ++e2)
        #pragma unroll
        for (int jj = 0; jj < 4; ++jj)
            #pragma unroll
            for (int i = 0; i < 4; ++i) roll[e2][jj][i] = 0.f;

    const int tM = tid & 63;
    const int kg = wave << 4;
    const float4* coefv = (const float4*)coef;

    __syncthreads();

    for (int w = wbeg; w < wbeg + 9; ++w) {
        const int buf = w & 1;
        // ---- M1 basis (A-operand, shared) -> M1t[buf] ----
        {
            unsigned int mpk[8];
            #pragma unroll
            for (int j2 = 0; j2 < 8; ++j2) {
                unsigned int pk = 0;
                #pragma unroll
                for (int sdx = 0; sdx < 2; ++sdx) {
                    int k = kg + j2 * 2 + sdx;
                    int m = k & 31;
                    int r = Bns[w * 32 + m];
                    float sc = (r == 0 || r == 32) ? 0.015625f : 0.03125f;
                    int idx = (r * tM) & 63;
                    float val = (k < 32) ? (cosT[idx] * sc) : (-sinT[idx] * sc);
                    pk |= (unsigned int)f2bf(val) << (16 * sdx);
                }
                mpk[j2] = pk;
            }
            uint4* dm = (uint4*)&M1t[buf][tM * 72 + kg];
            dm[0] = make_uint4(mpk[0], mpk[1], mpk[2], mpk[3]);
            dm[1] = make_uint4(mpk[4], mpk[5], mpk[6], mpk[7]);
        }

        // ---- B-fragment (Y) per-lane in registers: re/im at m=q*8..q*8+7 ----
        unsigned int wre[2][4], wim[2][4];
        #pragma unroll
        for (int e2 = 0; e2 < 2; ++e2) {
            const int e = ebase[e2];
            float4 cA = coefv[(size_t)(w * 128 + e) * 2];
            float4 cB = coefv[(size_t)(w * 128 + e) * 2 + 1];
            #pragma unroll
            for (int p = 0; p < 4; ++p) {
                int o = w * 32 + q * 8 + p * 2;
                float2 vmr = *(const float2*)&Vre[o];
                float2 vmi = *(const float2*)&Vim[o];
                float2 vlr = make_float2(0.f, 0.f), vli = vlr;
                float2 vpr = vlr, vpi = vlr;
                if (w > 0)  { vlr = *(const float2*)&Vre[o - 32];
                              vli = *(const float2*)&Vim[o - 32]; }
                if (w < 16) { vpr = *(const float2*)&Vre[o + 32];
                              vpi = *(const float2*)&Vim[o + 32]; }
                float rex = cB.z, rey = cB.z, imx = cB.w, imy = cB.w;
                rex = fmaf(vmr.x, cA.x, rex);  rey = fmaf(vmr.y, cA.x, rey);
                rex = fmaf(-vmi.x, cA.y, rex); rey = fmaf(-vmi.y, cA.y, rey);
                rex = fmaf(vlr.x, cA.z, rex);  rey = fmaf(vlr.y, cA.z, rey);
                rex = fmaf(-vli.x, cA.w, rex); rey = fmaf(-vli.y, cA.w, rey);
                rex = fmaf(vpr.x, cB.x, rex);  rey = fmaf(vpr.y, cB.x, rey);
                rex = fmaf(-vpi.x, cB.y, rex); rey = fmaf(-vpi.y, cB.y, rey);
                imx = fmaf(vmi.x, cA.x, imx);  imy = fmaf(vmi.y, cA.x, imy);
                imx = fmaf(vmr.x, cA.y, imx);  imy = fmaf(vmr.y, cA.y, imy);
                imx = fmaf(vli.x, cA.z, imx);  imy = fmaf(vli.y, cA.z, imy);
                imx = fmaf(vlr.x, cA.w, imx);  imy = fmaf(vlr.y, cA.w, imy);
                imx = fmaf(vpi.x, cB.x, imx);  imy = fmaf(vpi.y, cB.x, imy);
                imx = fmaf(vpr.x, cB.y, imx);  imy = fmaf(vpr.y, cB.y, imy);
                rex = fmaxf(rex, 0.f); rey = fmaxf(rey, 0.f);
                imx = fmaxf(imx, 0.f); imy = fmaxf(imy, 0.f);
                wre[e2][p] = (unsigned int)f2bf(rex) | ((unsigned int)f2bf(rey) << 16);
                wim[e2][p] = (unsigned int)f2bf(imx) | ((unsigned int)f2bf(imy) << 16);
            }
        }
        __syncthreads();   // M1t[buf] writes visible; the only barrier this iter

        // ---- MFMA: OUT[t][e] = M1[t][k] @ Ycomb[k][e] ----
        v4f acc[4][2];
        #pragma unroll
        for (int tt = 0; tt < 4; ++tt)
            #pragma unroll
            for (int e2 = 0; e2 < 2; ++e2) acc[tt][e2] = (v4f){0.f, 0.f, 0.f, 0.f};
        #pragma unroll
        for (int ks = 0; ks < 2; ++ks) {
            v8s bfr[2];
            #pragma unroll
            for (int e2 = 0; e2 < 2; ++e2) {
                union { uint4 u; v8s v; } cvt;
                cvt.u = ks == 0
                    ? make_uint4(wre[e2][0], wre[e2][1], wre[e2][2], wre[e2][3])
                    : make_uint4(wim[e2][0], wim[e2][1], wim[e2][2], wim[e2][3]);
                bfr[e2] = cvt.v;
            }
            #pragma unroll
            for (int tt = 0; tt < 4; ++tt) {
                v8s af = *(const v8s*)&M1t[buf][(tt * 16 + l15) * 72 + ks * 32 + q * 8];
                #pragma unroll
                for (int e2 = 0; e2 < 2; ++e2)
                    acc[tt][e2] = __builtin_amdgcn_mfma_f32_16x16x32_bf16(
                        af, bfr[e2], acc[tt][e2], 0, 0, 0);
            }
        }

        // ---- OLA ----
        if ((w & 1) == 0) {
            MID_ROLL(0, 1, 2, 3);
            if (w > wbeg) {
                MID_FLUSH(0, 1);
            } else {
                // first window of this half: slots 0,1 belong to the other
                // half (or pad) — discard (verified pad-discard logic)
                #pragma unroll
                for (int e2 = 0; e2 < 2; ++e2)
                    #pragma unroll
                    for (int i = 0; i < 4; ++i) {
                        roll[e2][0][i] = 0.f; roll[e2][1][i] = 0.f;
                    }
            }
        } else {
            MID_ROLL(2, 3, 0, 1);
            MID_FLUSH(2, 3);
        }
        // no trailing barrier: next iter writes M1t[buf^1], which is only
        // overwritten again after every wave passed the next barrier
    }
}

// ---------------------------------------------------------------------------
// Kernel D: FC1 split-K GEMM, 256x256 tile, 512 threads, BK=32, dbuf DMA.
// Flat grid 4*KS with XCD-pairing swizzle. Partials bf16.
// ---------------------------------------------------------------------------
__global__ __launch_bounds__(512) void gemm_kernel(
    const unsigned short* __restrict__ Aimg, const unsigned short* __restrict__ w1p,
    unsigned short* __restrict__ hp, int iters, int KS)
{
    __shared__ unsigned short As[2][8192];
    __shared__ unsigned short Bs[2][8192];

    const int gid = blockIdx.x;
    const int xcd = gid & 7;
    const int u = gid >> 3;
    const int KS4 = KS >> 2;
    const int nt2 = (u >= KS4) ? 1 : 0;
    const int vv = u - nt2 * KS4;
    const int pid = vv * 8 + xcd;
    const int ks = pid >> 1;
    const int mt2 = pid & 1;

    const int tid = threadIdx.x;
    const int wave = tid >> 6, lane = tid & 63;
    const int l15 = lane & 15, q = lane >> 4;
    const int kb0 = ks * iters;

    const int isB = wave >> 2;
    const int sub = wave & 3;
    const unsigned short* gsrc = (isB
        ? w1p + ((size_t)(nt2 * 2 + (sub >> 1)) * 2048 + kb0) * 4096
        : Aimg + ((size_t)(mt2 * 2 + (sub >> 1)) * 2048 + kb0) * 4096)
        + (sub & 1) * 2048 + lane * 8;
    const int ldsoff = (sub >> 1) * 4096 + (sub & 1) * 2048;   // wave-uniform

    v4f acc[4][8];
    #pragma unroll
    for (int mf = 0; mf < 4; ++mf)
        #pragma unroll
        for (int nf = 0; nf < 8; ++nf) acc[mf][nf] = (v4f){0.f, 0.f, 0.f, 0.f};

    {
        unsigned short* dst = (isB ? Bs[0] : As[0]) + ldsoff;
        #pragma unroll
        for (int j = 0; j < 4; ++j) async16(gsrc + j * 512, dst + j * 512);
    }

    const int wm = wave >> 1, wn = wave & 1;
    const int ca = (q ^ ((l15 >> 2) & 3)) * 8;
    const int rA = (wm >> 1) * 4096 + ((wm & 1) * 64 + l15) * 32 + ca;
    const int rB = wn * 4096 + l15 * 32 + ca;

    for (int it = 0; it < iters; ++it) {
        __syncthreads();
        if (it + 1 < iters) {
            const unsigned short* src = gsrc + (size_t)(it + 1) * 4096;
            unsigned short* dst = (isB ? Bs[(it + 1) & 1] : As[(it + 1) & 1]) + ldsoff;
            #pragma unroll
            for (int j = 0; j < 4; ++j) async16(src + j * 512, dst + j * 512);
        }
        const int cur = it & 1;
        v8s af[4], bf[8];
        #pragma unroll
        for (int f = 0; f < 4; ++f) af[f] = *(const v8s*)&As[cur][rA + f * 512];
        #pragma unroll
        for (int nf = 0; nf < 8; ++nf) bf[nf] = *(const v8s*)&Bs[cur][rB + nf * 512];
        #pragma unroll
        for (int mf = 0; mf < 4; ++mf)
            #pragma unroll
            for (int nf = 0; nf < 8; ++nf)
                acc[mf][nf] = __builtin_amdgcn_mfma_f32_16x16x32_bf16(
                    af[mf], bf[nf], acc[mf][nf], 0, 0, 0);
    }

    #pragma unroll
    for (int mf = 0; mf < 4; ++mf)
        #pragma unroll
        for (int nf = 0; nf < 8; ++nf) {
            int row = mt2 * 256 + wm * 64 + mf * 16 + q * 4;
            int col = nt2 * 256 + wn * 128 + nf * 16 + l15;
            unsigned short* dst = hp + ((size_t)ks * 512 + row) * 512 + col;
            #pragma unroll
            for (int i = 0; i < 4; ++i) dst[(size_t)i * 512] = f2bf(acc[mf][nf][i]);
        }
}

// ---------------------------------------------------------------------------
// Kernel E (fused): per row — reduce bf16 split-K partials + b1 + leaky into
// LDS, then FC2 matvec + b2 -> out[b][p][n]. grid 512, 256 thr.
// ---------------------------------------------------------------------------
__global__ __launch_bounds__(256) void fc2_kernel(
    const unsigned short* __restrict__ hp, const float* __restrict__ b1,
    const float* __restrict__ w2, const float* __restrict__ b2,
    float* __restrict__ out, int KS)
{
    __shared__ float hbuf[512];
    const int row = blockIdx.x;
    const int tid = threadIdx.x;

    const unsigned int* base = (const unsigned int*)(hp + (size_t)row * 512) + tid;
    float a0 = 0.f, a1 = 0.f;
    #pragma unroll 8
    for (int k = 0; k < KS; ++k) {
        unsigned int v = base[(size_t)k * 131072];   // 512*512 ushort / 2
        a0 += bf2f((unsigned short)(v & 0xffff));
        a1 += bf2f((unsigned short)(v >> 16));
    }
    float s0 = a0 + b1[tid * 2];
    float s1 = a1 + b1[tid * 2 + 1];
    hbuf[tid * 2]     = (s0 > 0.f) ? s0 : 0.01f * s0;
    hbuf[tid * 2 + 1] = (s1 > 0.f) ? s1 : 0.01f * s1;
    __syncthreads();

    if (tid < 96) {
        float a = b2[tid];
        #pragma unroll 8
        for (int h = 0; h < 512; ++h) a = fmaf(hbuf[h], w2[h * 96 + tid], a);
        int b = row >> 5, n = row & 31;
        out[(size_t)b * 3072 + tid * 32 + n] = a;
    }
}

// ---------------------------------------------------------------------------
extern "C" void kernel_launch(void* const* d_in, const int* in_sizes, int n_in,
                              void* d_out, int out_size, void* d_ws, size_t ws_size,
                              hipStream_t stream) {
    const float* x   = (const float*)d_in[0];
    const float* emb = (const float*)d_in[1];
    const float* Wr  = (const float*)d_in[2];
    const float* Wi  = (const float*)d_in[3];
    const float* Wrl = (const float*)d_in[4];
    const float* Wil = (const float*)d_in[5];
    const float* Wrr = (const float*)d_in[6];
    const float* Wir = (const float*)d_in[7];
    const float* br  = (const float*)d_in[8];
    const float* bi  = (const float*)d_in[9];
    const float* w1  = (const float*)d_in[10];
    const float* b1  = (const float*)d_in[11];
    const float* w2  = (const float*)d_in[12];
    const float* b2  = (const float*)d_in[13];

    char* ws = (char*)d_ws;
    float* coef          = (float*)(ws + OFF_COEF);
    float2* V            = (float2*)(ws + OFF_V);
    int* bins            = (int*)(ws + OFF_BINS);
    unsigned short* Aimg = (unsigned short*)(ws + OFF_AIMG);
    unsigned short* w1p  = (unsigned short*)(ws + OFF_W1P);
    unsigned short* hpp  = (unsigned short*)(ws + OFF_HP);

    int KS = 64;
    size_t hp_bytes = (size_t)KS * 512 * 512 * 2;
    if (OFF_HP + hp_bytes > ws_size) {
        KS = 32; hp_bytes = (size_t)KS * 512 * 512 * 2;
    }
    int iters = 2048 / KS;

    coef_kernel<<<dim3(17, 8), dim3(128), 0, stream>>>(
        emb, Wr, Wi, Wrl, Wil, Wrr, Wir, br, bi, coef);
    cvt_kernel<<<dim3(2048, 4), dim3(256), 0, stream>>>(w1, w1p);
    stft_kernel<<<dim3(512), dim3(256), 0, stream>>>(x, V, bins);
    mid_kernel<<<dim3(1024), dim3(256), 0, stream>>>(x, emb, coef, V, bins, Aimg);
    gemm_kernel<<<dim3(4 * KS), dim3(512), 0, stream>>>(Aimg, w1p, hpp, iters, KS);
    fc2_kernel<<<dim3(512), dim3(256), 0, stream>>>(hpp, b1, w2, b2, (float*)d_out, KS);
}

// Round 8
// 412.691 us; speedup vs baseline: 1.0164x; 1.0164x over previous
//
#include <hip/hip_runtime.h>
#include <hip/hip_bf16.h>

// B=16, SEQ=512, NF=32, E=128, HID=512, PRED=96, N_FFT=64, HOP=32, TOPM=32
// W=17, F=33, LAM=0.01
#define LAM 0.01f

typedef __attribute__((ext_vector_type(8))) short v8s;
typedef __attribute__((ext_vector_type(4))) float v4f;

static __device__ __forceinline__ unsigned short f2bf(float f) {
    union { float f; unsigned int u; } v; v.f = f;
    unsigned int u = v.u;
    u += 0x7fffu + ((u >> 16) & 1u);   // RNE
    return (unsigned short)(u >> 16);
}
static __device__ __forceinline__ float bf2f(unsigned short h) {
    union { unsigned int u; float f; } c; c.u = ((unsigned int)h) << 16;
    return c.f;
}
// packed 2xf32 -> 2xbf16 (v_cvt_pk_bf16_f32 on gfx950); lo=a, hi=b
static __device__ __forceinline__ unsigned int pkbf(float a, float b) {
    union { __hip_bfloat162 h; unsigned int u; } c;
    c.h = __float22bfloat162_rn(float2{a, b});
    return c.u;
}

// async global->LDS DMA, 16 B/lane; lds base wave-uniform, lane i -> base+16i
static __device__ __forceinline__ void async16(const void* g, void* l) {
    __builtin_amdgcn_global_load_lds(
        (const __attribute__((address_space(1))) unsigned int*)g,
        (__attribute__((address_space(3))) unsigned int*)l, 16, 0, 0);
}

// Workspace layout (bytes)
#define OFF_COEF 0ull
#define OFF_V    69632ull
#define OFF_BINS 2297856ull
#define OFF_AIMG 3411968ull                     // 512*65536 bf16 swizzled = 67,108,864
#define OFF_W1P  70520832ull                    // 65536*512 bf16 swizzled = 67,108,864
#define OFF_HP   137629696ull                   // KS*512*512*2 (bf16 partials)

// ---------------------------------------------------------------------------
// Kernel A: coef[w][e][j]: j=0..5 -> emb . Wj[w,:,e]; j=6 -> br-LAM; j=7 -> bi-LAM
// ---------------------------------------------------------------------------
__global__ __launch_bounds__(128) void coef_kernel(
    const float* __restrict__ emb,
    const float* __restrict__ Wr, const float* __restrict__ Wi,
    const float* __restrict__ Wrl, const float* __restrict__ Wil,
    const float* __restrict__ Wrr, const float* __restrict__ Wir,
    const float* __restrict__ br, const float* __restrict__ bi,
    float* __restrict__ coef)
{
    int w = blockIdx.x, j = blockIdx.y, e = threadIdx.x;
    float out;
    if (j < 6) {
        const float* Wj;
        switch (j) {
            case 0: Wj = Wr; break; case 1: Wj = Wi; break;
            case 2: Wj = Wrl; break; case 3: Wj = Wil; break;
            case 4: Wj = Wrr; break; default: Wj = Wir; break;
        }
        const float* p = Wj + (size_t)w * 16384 + e;
        float acc = 0.f;
        #pragma unroll 8
        for (int ep = 0; ep < 128; ++ep) acc = fmaf(emb[ep], p[ep * 128], acc);
        out = acc;
    } else if (j == 6) {
        out = br[w * 128 + e] - LAM;
    } else {
        out = bi[w * 128 + e] - LAM;
    }
    coef[((size_t)(w * 128 + e)) * 8 + j] = out;
}

// ---------------------------------------------------------------------------
// Kernel B: per (b,n): windowed 64-pt DFT, 17x33 bins, rank |S|, store top-32.
// ---------------------------------------------------------------------------
__global__ __launch_bounds__(256) void stft_kernel(
    const float* __restrict__ x, float2* __restrict__ V, int* __restrict__ bins)
{
    __shared__ float sig[576];
    __shared__ float winT[64];
    __shared__ float2 tw[64];
    __shared__ float2 Sbuf[17 * 33];
    __shared__ float absb[17 * 33];

    const int blk = blockIdx.x;
    const int b = blk >> 5, n = blk & 31;
    const int tid = threadIdx.x;
    const float C64 = 0.09817477042468103f; // 2*pi/64

    if (tid < 64) {
        float ang = (float)tid * C64;
        winT[tid] = 0.5f - 0.5f * cosf(ang);
        tw[tid] = make_float2(cosf(ang), sinf(ang));   // accurate libm: top-k tie safety
    }
    for (int l = tid; l < 576; l += 256) {
        int t = (l < 32) ? (32 - l) : ((l < 544) ? (l - 32) : (1054 - l)); // reflect
        sig[l] = x[(size_t)b * 16384 + t * 32 + n];
    }
    __syncthreads();

    for (int task = tid; task < 561; task += 256) {
        int w = task / 33, f = task - w * 33;
        float sr = 0.f, si = 0.f;
        int base = w * 32;
        for (int t = 0; t < 64; ++t) {
            float sw = sig[base + t] * winT[t];
            float2 cs = tw[(f * t) & 63];
            sr = fmaf(sw, cs.x, sr);
            si = fmaf(sw, -cs.y, si);
        }
        Sbuf[task] = make_float2(sr, si);
        absb[task] = sqrtf(fmaf(sr, sr, si * si));
    }
    __syncthreads();

    for (int task = tid; task < 561; task += 256) {
        int w = task / 33, f = task - w * 33;
        float a = absb[task];
        int base = w * 33, rank = 0;
        for (int j = 0; j < 33; ++j) {
            float aj = absb[base + j];
            rank += (aj > a) || (aj == a && j < f);   // stable
        }
        if (rank < 32) {
            size_t o = ((size_t)blk * 17 + w) * 32 + rank;
            V[o] = Sbuf[task];
            bins[o] = f;
        }
    }
}

// ---------------------------------------------------------------------------
// Kernel W-cvt: w1 f32 -> bf16 swizzled DMA image.
// Image: [nt(4)][kb(2048)][n'(128)][32k]; chunk c_log at pos c_log^((n'>>2)&3).
// ---------------------------------------------------------------------------
__global__ __launch_bounds__(256) void cvt_kernel(
    const float* __restrict__ w1, unsigned short* __restrict__ w1p)
{
    __shared__ float T[32][132];
    const int kb = blockIdx.x, nt = blockIdx.y;
    const int tid = threadIdx.x;

    #pragma unroll
    for (int p = 0; p < 4; ++p) {
        int r = (tid >> 5) + p * 8;
        int c = (tid & 31) * 4;
        float4 v = *(const float4*)&w1[((size_t)(kb * 32 + r)) * 512 + nt * 128 + c];
        T[r][c] = v.x; T[r][c + 1] = v.y; T[r][c + 2] = v.z; T[r][c + 3] = v.w;
    }
    __syncthreads();

    unsigned short* dst = w1p + ((size_t)nt * 2048 + kb) * 4096;
    #pragma unroll
    for (int p = 0; p < 2; ++p) {
        int pos = tid + 256 * p;            // 16-B chunk index
        int np = pos >> 2, cs = pos & 3;
        int clog = cs ^ ((np >> 2) & 3);
        unsigned int pk[4];
        #pragma unroll
        for (int j2 = 0; j2 < 4; ++j2)
            pk[j2] = pkbf(T[clog * 8 + j2 * 2][np], T[clog * 8 + j2 * 2 + 1][np]);
        *(uint4*)&dst[pos * 8] = make_uint4(pk[0], pk[1], pk[2], pk[3]);
    }
}

// ---------------------------------------------------------------------------
// Kernel C: mid — R5 structure (best measured) + v_cvt_pk_bf16_f32 packing.
// Per-(b,n) inputs (V, bins, x-row) preloaded to LDS; Y via LDS (Yt);
// MFMA 64x128; register OLA; write A-image bf16 swizzled. grid 512, 256 thr.
// ---------------------------------------------------------------------------
#define MID_ROLL(J0, J1, J2, J3)                                                \
    {                                                                           \
        _Pragma("unroll") for (int e2 = 0; e2 < 2; ++e2)                        \
        _Pragma("unroll") for (int i = 0; i < 4; ++i) {                         \
            roll[e2][J0][i] = fmaf(acc[0][e2][i], win16[0][i], roll[e2][J0][i]);\
            roll[e2][J1][i] = fmaf(acc[1][e2][i], win16[1][i], roll[e2][J1][i]);\
            roll[e2][J2][i] = fmaf(acc[2][e2][i], win16[2][i], roll[e2][J2][i]);\
            roll[e2][J3][i] = fmaf(acc[3][e2][i], win16[3][i], roll[e2][J3][i]);\
        }                                                                       \
    }

#define MID_FLUSH(JJA, JJB)                                                     \
    {                                                                           \
        _Pragma("unroll") for (int i = 0; i < 4; ++i) {                         \
            int tp = 32 * (w - 1) + q * 4 + i;                                  \
            float xb = xs[tp];                                                  \
            _Pragma("unroll") for (int e2 = 0; e2 < 2; ++e2) {                  \
                float val = fmaf(roll[e2][JJA][i], renv[0][i], xb * emb2[e2]);  \
                Aimg[cbase[e2] + (size_t)tp * 16384] = f2bf(val);               \
                roll[e2][JJA][i] = 0.f;                                         \
            }                                                                   \
            int tp2 = tp + 16;                                                  \
            float xb2 = xs[tp2];                                                \
            _Pragma("unroll") for (int e2 = 0; e2 < 2; ++e2) {                  \
                float val = fmaf(roll[e2][JJB][i], renv[1][i], xb2 * emb2[e2]); \
                Aimg[cbase[e2] + (size_t)tp2 * 16384] = f2bf(val);              \
                roll[e2][JJB][i] = 0.f;                                         \
            }                                                                   \
        }                                                                       \
    }

__global__ __launch_bounds__(256) void mid_kernel(
    const float* __restrict__ x, const float* __restrict__ emb,
    const float* __restrict__ coef, const float2* __restrict__ V,
    const int* __restrict__ bins, unsigned short* __restrict__ Aimg)
{
    __shared__ unsigned short M1t[64 * 72];
    __shared__ unsigned short Yt[128 * 72];
    __shared__ float cosT[64];
    __shared__ float sinT[64];
    __shared__ float2 Vs[17 * 32];
    __shared__ int Bns[17 * 32];
    __shared__ float xs[512];

    const int blk = blockIdx.x;
    const int b = blk >> 5, n = blk & 31;
    const int tid = threadIdx.x;
    const int wave = tid >> 6, lane = tid & 63, l15 = lane & 15, q = lane >> 4;
    const float C64 = 0.09817477042468103f;

    if (tid < 64) {
        float ang = (float)tid * C64;
        cosT[tid] = __cosf(ang);
        sinT[tid] = __sinf(ang);
    }
    {
        const float2* Vg = V + (size_t)blk * 544;
        const int* Bg = bins + (size_t)blk * 544;
        for (int i = tid; i < 544; i += 256) { Vs[i] = Vg[i]; Bns[i] = Bg[i]; }
        for (int i = tid; i < 512; i += 256) xs[i] = x[(size_t)b * 16384 + i * 32 + n];
    }

    float win16[4][4];
    #pragma unroll
    for (int tt = 0; tt < 4; ++tt)
        #pragma unroll
        for (int i = 0; i < 4; ++i) {
            int t = tt * 16 + q * 4 + i;
            win16[tt][i] = 0.5f - 0.5f * __cosf((float)t * C64);
        }
    float renv[2][4];
    #pragma unroll
    for (int hf = 0; hf < 2; ++hf)
        #pragma unroll
        for (int i = 0; i < 4; ++i) {
            int k = hf * 16 + q * 4 + i;
            float w0 = 0.5f - 0.5f * __cosf((float)k * C64);
            float w1v = 0.5f - 0.5f * __cosf((float)(k + 32) * C64);
            renv[hf][i] = 1.0f / (w0 * w0 + w1v * w1v);
        }
    int ebase[2];
    float emb2[2];
    size_t cbase[2];
    const int mt = blk >> 7, mp = blk & 127, s = (mp >> 2) & 3;
    #pragma unroll
    for (int e2 = 0; e2 < 2; ++e2) {
        ebase[e2] = (wave * 2 + e2) * 16 + l15;
        emb2[e2] = emb[ebase[e2]];
        int e = ebase[e2];
        int echunk = e >> 5, clog = (e >> 3) & 3, cs = clog ^ s, el = e & 7;
        cbase[e2] = ((size_t)mt * 2048 + echunk) * 4096 + mp * 32 + cs * 8 + el;
    }

    float roll[2][4][4];
    #pragma unroll
    for (int e2 = 0; e2 < 2; ++e2)
        #pragma unroll
        for (int jj = 0; jj < 4; ++jj)
            #pragma unroll
            for (int i = 0; i < 4; ++i) roll[e2][jj][i] = 0.f;

    const int e1 = tid & 127;
    const int mg = (tid >> 7) << 4;
    const int tM = tid & 63;
    const int kg = wave << 4;

    __syncthreads();

    for (int w = 0; w < 17; ++w) {
        // ---- Y (bf16, packed cvt) ----
        {
            const float4* cf = (const float4*)(coef + ((size_t)(w * 128 + e1)) * 8);
            float4 cA = cf[0];
            float4 cB = cf[1];
            unsigned int rep[8], imp[8];
            #pragma unroll
            for (int j2 = 0; j2 < 8; ++j2) {
                float rev[2], imv[2];
                #pragma unroll
                for (int sdx = 0; sdx < 2; ++sdx) {
                    int m = mg + j2 * 2 + sdx;
                    float2 vm = Vs[w * 32 + m];
                    float2 vl = (w > 0) ? Vs[(w - 1) * 32 + m] : make_float2(0.f, 0.f);
                    float2 vp = (w < 16) ? Vs[(w + 1) * 32 + m] : make_float2(0.f, 0.f);
                    float re = cB.z;
                    re = fmaf(vm.x, cA.x, re); re = fmaf(-vm.y, cA.y, re);
                    re = fmaf(vl.x, cA.z, re); re = fmaf(-vl.y, cA.w, re);
                    re = fmaf(vp.x, cB.x, re); re = fmaf(-vp.y, cB.y, re);
                    float im = cB.w;
                    im = fmaf(vm.y, cA.x, im); im = fmaf(vm.x, cA.y, im);
                    im = fmaf(vl.y, cA.z, im); im = fmaf(vl.x, cA.w, im);
                    im = fmaf(vp.y, cB.x, im); im = fmaf(vp.x, cB.y, im);
                    rev[sdx] = fmaxf(re, 0.f);
                    imv[sdx] = fmaxf(im, 0.f);
                }
                rep[j2] = pkbf(rev[0], rev[1]);
                imp[j2] = pkbf(imv[0], imv[1]);
            }
            uint4* dr = (uint4*)&Yt[e1 * 72 + mg];
            dr[0] = make_uint4(rep[0], rep[1], rep[2], rep[3]);
            dr[1] = make_uint4(rep[4], rep[5], rep[6], rep[7]);
            uint4* di = (uint4*)&Yt[e1 * 72 + 32 + mg];
            di[0] = make_uint4(imp[0], imp[1], imp[2], imp[3]);
            di[1] = make_uint4(imp[4], imp[5], imp[6], imp[7]);
        }
        // ---- M1 basis (packed cvt) ----
        {
            unsigned int mpk[8];
            #pragma unroll
            for (int j2 = 0; j2 < 8; ++j2) {
                float vv[2];
                #pragma unroll
                for (int sdx = 0; sdx < 2; ++sdx) {
                    int k = kg + j2 * 2 + sdx;
                    int m = k & 31;
                    int r = Bns[w * 32 + m];
                    float sc = (r == 0 || r == 32) ? 0.015625f : 0.03125f;
                    int idx = (r * tM) & 63;
                    vv[sdx] = (k < 32) ? (cosT[idx] * sc) : (-sinT[idx] * sc);
                }
                mpk[j2] = pkbf(vv[0], vv[1]);
            }
            uint4* dm = (uint4*)&M1t[tM * 72 + kg];
            dm[0] = make_uint4(mpk[0], mpk[1], mpk[2], mpk[3]);
            dm[1] = make_uint4(mpk[4], mpk[5], mpk[6], mpk[7]);
        }
        __syncthreads();

        v4f acc[4][2];
        #pragma unroll
        for (int tt = 0; tt < 4; ++tt)
            #pragma unroll
            for (int e2 = 0; e2 < 2; ++e2) acc[tt][e2] = (v4f){0.f, 0.f, 0.f, 0.f};
        #pragma unroll
        for (int ks = 0; ks < 2; ++ks) {
            v8s bfr[2];
            #pragma unroll
            for (int e2 = 0; e2 < 2; ++e2)
                bfr[e2] = *(const v8s*)&Yt[ebase[e2] * 72 + ks * 32 + q * 8];
            #pragma unroll
            for (int tt = 0; tt < 4; ++tt) {
                v8s af = *(const v8s*)&M1t[(tt * 16 + l15) * 72 + ks * 32 + q * 8];
                #pragma unroll
                for (int e2 = 0; e2 < 2; ++e2)
                    acc[tt][e2] = __builtin_amdgcn_mfma_f32_16x16x32_bf16(
                        af, bfr[e2], acc[tt][e2], 0, 0, 0);
            }
        }

        if ((w & 1) == 0) {
            MID_ROLL(0, 1, 2, 3);
            if (w > 0) {
                MID_FLUSH(0, 1);
            } else {
                // chunks 0,1 (abs samples [0,32)) are pad-trimmed: discard
                #pragma unroll
                for (int e2 = 0; e2 < 2; ++e2)
                    #pragma unroll
                    for (int i = 0; i < 4; ++i) {
                        roll[e2][0][i] = 0.f; roll[e2][1][i] = 0.f;
                    }
            }
        } else {
            MID_ROLL(2, 3, 0, 1);
            MID_FLUSH(2, 3);
        }
        __syncthreads();
    }
}

// ---------------------------------------------------------------------------
// Kernel D: FC1 split-K GEMM, 256x256 tile, 512 threads, BK=32, dbuf DMA.
// Flat grid 4*KS with XCD-pairing swizzle. Partials bf16, layout [row][ks][hid].
// ---------------------------------------------------------------------------
__global__ __launch_bounds__(512) void gemm_kernel(
    const unsigned short* __restrict__ Aimg, const unsigned short* __restrict__ w1p,
    unsigned short* __restrict__ hp, int iters, int KS)
{
    __shared__ unsigned short As[2][8192];
    __shared__ unsigned short Bs[2][8192];

    const int gid = blockIdx.x;
    const int xcd = gid & 7;
    const int u = gid >> 3;
    const int KS4 = KS >> 2;
    const int nt2 = (u >= KS4) ? 1 : 0;
    const int vv = u - nt2 * KS4;
    const int pid = vv * 8 + xcd;
    const int ks = pid >> 1;
    const int mt2 = pid & 1;

    const int tid = threadIdx.x;
    const int wave = tid >> 6, lane = tid & 63;
    const int l15 = lane & 15, q = lane >> 4;
    const int kb0 = ks * iters;

    const int isB = wave >> 2;
    const int sub = wave & 3;
    const unsigned short* gsrc = (isB
        ? w1p + ((size_t)(nt2 * 2 + (sub >> 1)) * 2048 + kb0) * 4096
        : Aimg + ((size_t)(mt2 * 2 + (sub >> 1)) * 2048 + kb0) * 4096)
        + (sub & 1) * 2048 + lane * 8;
    const int ldsoff = (sub >> 1) * 4096 + (sub & 1) * 2048;   // wave-uniform

    v4f acc[4][8];
    #pragma unroll
    for (int mf = 0; mf < 4; ++mf)
        #pragma unroll
        for (int nf = 0; nf < 8; ++nf) acc[mf][nf] = (v4f){0.f, 0.f, 0.f, 0.f};

    {
        unsigned short* dst = (isB ? Bs[0] : As[0]) + ldsoff;
        #pragma unroll
        for (int j = 0; j < 4; ++j) async16(gsrc + j * 512, dst + j * 512);
    }

    const int wm = wave >> 1, wn = wave & 1;
    const int ca = (q ^ ((l15 >> 2) & 3)) * 8;
    const int rA = (wm >> 1) * 4096 + ((wm & 1) * 64 + l15) * 32 + ca;
    const int rB = wn * 4096 + l15 * 32 + ca;

    for (int it = 0; it < iters; ++it) {
        __syncthreads();
        if (it + 1 < iters) {
            const unsigned short* src = gsrc + (size_t)(it + 1) * 4096;
            unsigned short* dst = (isB ? Bs[(it + 1) & 1] : As[(it + 1) & 1]) + ldsoff;
            #pragma unroll
            for (int j = 0; j < 4; ++j) async16(src + j * 512, dst + j * 512);
        }
        const int cur = it & 1;
        v8s af[4], bf[8];
        #pragma unroll
        for (int f = 0; f < 4; ++f) af[f] = *(const v8s*)&As[cur][rA + f * 512];
        #pragma unroll
        for (int nf = 0; nf < 8; ++nf) bf[nf] = *(const v8s*)&Bs[cur][rB + nf * 512];
        #pragma unroll
        for (int mf = 0; mf < 4; ++mf)
            #pragma unroll
            for (int nf = 0; nf < 8; ++nf)
                acc[mf][nf] = __builtin_amdgcn_mfma_f32_16x16x32_bf16(
                    af[mf], bf[nf], acc[mf][nf], 0, 0, 0);
    }

    #pragma unroll
    for (int mf = 0; mf < 4; ++mf)
        #pragma unroll
        for (int nf = 0; nf < 8; ++nf) {
            int row = mt2 * 256 + wm * 64 + mf * 16 + q * 4;
            int col = nt2 * 256 + wn * 128 + nf * 16 + l15;
            // transposed: hp[row][ks][hid] -> fc2 reads 64KB contiguous/row
            unsigned short* dst = hp + ((size_t)row * KS + ks) * 512 + col;
            #pragma unroll
            for (int i = 0; i < 4; ++i)
                dst[(size_t)i * KS * 512] = f2bf(acc[mf][nf][i]);
        }
}

// ---------------------------------------------------------------------------
// Kernel E (fused): per row — reduce bf16 split-K partials (contiguous 64KB)
// + b1 + leaky into LDS, then FC2 matvec + b2 -> out[b][p][n]. grid 512, 256 thr.
// ---------------------------------------------------------------------------
__global__ __launch_bounds__(256) void fc2_kernel(
    const unsigned short* __restrict__ hp, const float* __restrict__ b1,
    const float* __restrict__ w2, const float* __restrict__ b2,
    float* __restrict__ out, int KS)
{
    __shared__ float hbuf[512];
    const int row = blockIdx.x;
    const int tid = threadIdx.x;

    // thread t owns hids {2t, 2t+1}; hp row-major [row][ks][hid]
    const unsigned int* base = (const unsigned int*)(hp + (size_t)row * KS * 512) + tid;
    float a0 = 0.f, a1 = 0.f;
    #pragma unroll 8
    for (int k = 0; k < KS; ++k) {
        unsigned int v = base[k * 256];   // 512 ushort = 256 uint per slice
        a0 += bf2f((unsigned short)(v & 0xffff));
        a1 += bf2f((unsigned short)(v >> 16));
    }
    float s0 = a0 + b1[tid * 2];
    float s1 = a1 + b1[tid * 2 + 1];
    hbuf[tid * 2]     = (s0 > 0.f) ? s0 : 0.01f * s0;
    hbuf[tid * 2 + 1] = (s1 > 0.f) ? s1 : 0.01f * s1;
    __syncthreads();

    if (tid < 96) {
        float a = b2[tid];
        #pragma unroll 8
        for (int h = 0; h < 512; ++h) a = fmaf(hbuf[h], w2[h * 96 + tid], a);
        int b = row >> 5, n = row & 31;
        out[(size_t)b * 3072 + tid * 32 + n] = a;
    }
}

// ---------------------------------------------------------------------------
extern "C" void kernel_launch(void* const* d_in, const int* in_sizes, int n_in,
                              void* d_out, int out_size, void* d_ws, size_t ws_size,
                              hipStream_t stream) {
    const float* x   = (const float*)d_in[0];
    const float* emb = (const float*)d_in[1];
    const float* Wr  = (const float*)d_in[2];
    const float* Wi  = (const float*)d_in[3];
    const float* Wrl = (const float*)d_in[4];
    const float* Wil = (const float*)d_in[5];
    const float* Wrr = (const float*)d_in[6];
    const float* Wir = (const float*)d_in[7];
    const float* br  = (const float*)d_in[8];
    const float* bi  = (const float*)d_in[9];
    const float* w1  = (const float*)d_in[10];
    const float* b1  = (const float*)d_in[11];
    const float* w2  = (const float*)d_in[12];
    const float* b2  = (const float*)d_in[13];

    char* ws = (char*)d_ws;
    float* coef          = (float*)(ws + OFF_COEF);
    float2* V            = (float2*)(ws + OFF_V);
    int* bins            = (int*)(ws + OFF_BINS);
    unsigned short* Aimg = (unsigned short*)(ws + OFF_AIMG);
    unsigned short* w1p  = (unsigned short*)(ws + OFF_W1P);
    unsigned short* hpp  = (unsigned short*)(ws + OFF_HP);

    int KS = 64;
    size_t hp_bytes = (size_t)KS * 512 * 512 * 2;
    if (OFF_HP + hp_bytes > ws_size) {
        KS = 32; hp_bytes = (size_t)KS * 512 * 512 * 2;
    }
    int iters = 2048 / KS;

    coef_kernel<<<dim3(17, 8), dim3(128), 0, stream>>>(
        emb, Wr, Wi, Wrl, Wil, Wrr, Wir, br, bi, coef);
    cvt_kernel<<<dim3(2048, 4), dim3(256), 0, stream>>>(w1, w1p);
    stft_kernel<<<dim3(512), dim3(256), 0, stream>>>(x, V, bins);
    mid_kernel<<<dim3(512), dim3(256), 0, stream>>>(x, emb, coef, V, bins, Aimg);
    gemm_kernel<<<dim3(4 * KS), dim3(512), 0, stream>>>(Aimg, w1p, hpp, iters, KS);
    fc2_kernel<<<dim3(512), dim3(256), 0, stream>>>(hpp, b1, w2, b2, (float*)d_out, KS);
}

// Round 9
// 405.783 us; speedup vs baseline: 1.0337x; 1.0170x over previous
//
#include <hip/hip_runtime.h>
#include <hip/hip_bf16.h>

// B=16, SEQ=512, NF=32, E=128, HID=512, PRED=96, N_FFT=64, HOP=32, TOPM=32
// W=17, F=33, LAM=0.01
#define LAM 0.01f

typedef __attribute__((ext_vector_type(8))) short v8s;
typedef __attribute__((ext_vector_type(4))) float v4f;

static __device__ __forceinline__ unsigned short f2bf(float f) {
    union { float f; unsigned int u; } v; v.f = f;
    unsigned int u = v.u;
    u += 0x7fffu + ((u >> 16) & 1u);   // RNE
    return (unsigned short)(u >> 16);
}
static __device__ __forceinline__ float bf2f(unsigned short h) {
    union { unsigned int u; float f; } c; c.u = ((unsigned int)h) << 16;
    return c.f;
}
// packed 2xf32 -> 2xbf16 (v_cvt_pk_bf16_f32 on gfx950); lo=a, hi=b
static __device__ __forceinline__ unsigned int pkbf(float a, float b) {
    union { __hip_bfloat162 h; unsigned int u; } c;
    c.h = __float22bfloat162_rn(float2{a, b});
    return c.u;
}

// async global->LDS DMA, 16 B/lane; lds base wave-uniform, lane i -> base+16i
static __device__ __forceinline__ void async16(const void* g, void* l) {
    __builtin_amdgcn_global_load_lds(
        (const __attribute__((address_space(1))) unsigned int*)g,
        (__attribute__((address_space(3))) unsigned int*)l, 16, 0, 0);
}

// Workspace layout (bytes)
#define OFF_COEF 0ull
#define OFF_V    69632ull
#define OFF_BINS 2297856ull
#define OFF_AIMG 3411968ull                     // 512*65536 bf16 swizzled = 67,108,864
#define OFF_W1P  70520832ull                    // 65536*512 bf16 swizzled = 67,108,864
#define OFF_HP   137629696ull                   // KS*512*512*2 (bf16 partials)

// ---------------------------------------------------------------------------
// Kernel A: coef[w][e][j]: j=0..5 -> emb . Wj[w,:,e]; j=6 -> br-LAM; j=7 -> bi-LAM
// ---------------------------------------------------------------------------
__global__ __launch_bounds__(128) void coef_kernel(
    const float* __restrict__ emb,
    const float* __restrict__ Wr, const float* __restrict__ Wi,
    const float* __restrict__ Wrl, const float* __restrict__ Wil,
    const float* __restrict__ Wrr, const float* __restrict__ Wir,
    const float* __restrict__ br, const float* __restrict__ bi,
    float* __restrict__ coef)
{
    int w = blockIdx.x, j = blockIdx.y, e = threadIdx.x;
    float out;
    if (j < 6) {
        const float* Wj;
        switch (j) {
            case 0: Wj = Wr; break; case 1: Wj = Wi; break;
            case 2: Wj = Wrl; break; case 3: Wj = Wil; break;
            case 4: Wj = Wrr; break; default: Wj = Wir; break;
        }
        const float* p = Wj + (size_t)w * 16384 + e;
        float acc = 0.f;
        #pragma unroll 8
        for (int ep = 0; ep < 128; ++ep) acc = fmaf(emb[ep], p[ep * 128], acc);
        out = acc;
    } else if (j == 6) {
        out = br[w * 128 + e] - LAM;
    } else {
        out = bi[w * 128 + e] - LAM;
    }
    coef[((size_t)(w * 128 + e)) * 8 + j] = out;
}

// ---------------------------------------------------------------------------
// Kernel B: per (b,n): windowed 64-pt DFT, 17x33 bins, rank |S|, store top-32.
// ---------------------------------------------------------------------------
__global__ __launch_bounds__(256) void stft_kernel(
    const float* __restrict__ x, float2* __restrict__ V, int* __restrict__ bins)
{
    __shared__ float sig[576];
    __shared__ float winT[64];
    __shared__ float2 tw[64];
    __shared__ float2 Sbuf[17 * 33];
    __shared__ float absb[17 * 33];

    const int blk = blockIdx.x;
    const int b = blk >> 5, n = blk & 31;
    const int tid = threadIdx.x;
    const float C64 = 0.09817477042468103f; // 2*pi/64

    if (tid < 64) {
        float ang = (float)tid * C64;
        winT[tid] = 0.5f - 0.5f * cosf(ang);
        tw[tid] = make_float2(cosf(ang), sinf(ang));   // accurate libm: top-k tie safety
    }
    for (int l = tid; l < 576; l += 256) {
        int t = (l < 32) ? (32 - l) : ((l < 544) ? (l - 32) : (1054 - l)); // reflect
        sig[l] = x[(size_t)b * 16384 + t * 32 + n];
    }
    __syncthreads();

    for (int task = tid; task < 561; task += 256) {
        int w = task / 33, f = task - w * 33;
        float sr = 0.f, si = 0.f;
        int base = w * 32;
        for (int t = 0; t < 64; ++t) {
            float sw = sig[base + t] * winT[t];
            float2 cs = tw[(f * t) & 63];
            sr = fmaf(sw, cs.x, sr);
            si = fmaf(sw, -cs.y, si);
        }
        Sbuf[task] = make_float2(sr, si);
        absb[task] = sqrtf(fmaf(sr, sr, si * si));
    }
    __syncthreads();

    for (int task = tid; task < 561; task += 256) {
        int w = task / 33, f = task - w * 33;
        float a = absb[task];
        int base = w * 33, rank = 0;
        for (int j = 0; j < 33; ++j) {
            float aj = absb[base + j];
            rank += (aj > a) || (aj == a && j < f);   // stable
        }
        if (rank < 32) {
            size_t o = ((size_t)blk * 17 + w) * 32 + rank;
            V[o] = Sbuf[task];
            bins[o] = f;
        }
    }
}

// ---------------------------------------------------------------------------
// Kernel W-cvt: w1 f32 -> bf16 swizzled DMA image.
// Image: [nt(4)][kb(2048)][n'(128)][32k]; chunk c_log at pos c_log^((n'>>2)&3).
// ---------------------------------------------------------------------------
__global__ __launch_bounds__(256) void cvt_kernel(
    const float* __restrict__ w1, unsigned short* __restrict__ w1p)
{
    __shared__ float T[32][132];
    const int kb = blockIdx.x, nt = blockIdx.y;
    const int tid = threadIdx.x;

    #pragma unroll
    for (int p = 0; p < 4; ++p) {
        int r = (tid >> 5) + p * 8;
        int c = (tid & 31) * 4;
        float4 v = *(const float4*)&w1[((size_t)(kb * 32 + r)) * 512 + nt * 128 + c];
        T[r][c] = v.x; T[r][c + 1] = v.y; T[r][c + 2] = v.z; T[r][c + 3] = v.w;
    }
    __syncthreads();

    unsigned short* dst = w1p + ((size_t)nt * 2048 + kb) * 4096;
    #pragma unroll
    for (int p = 0; p < 2; ++p) {
        int pos = tid + 256 * p;            // 16-B chunk index
        int np = pos >> 2, cs = pos & 3;
        int clog = cs ^ ((np >> 2) & 3);
        unsigned int pk[4];
        #pragma unroll
        for (int j2 = 0; j2 < 4; ++j2)
            pk[j2] = pkbf(T[clog * 8 + j2 * 2][np], T[clog * 8 + j2 * 2 + 1][np]);
        *(uint4*)&dst[pos * 8] = make_uint4(pk[0], pk[1], pk[2], pk[3]);
    }
}

// ---------------------------------------------------------------------------
// Kernel C: mid — R5 structure + R9 changes:
//  * Yt AND M1t double-buffered -> exactly ONE barrier per w-iteration.
//  * Zero-halo V table Vs2[19][32] (rows 0,18 = 0) -> unconditional vm/vl/vp.
// Per-(b,n) inputs preloaded to LDS; MFMA 64x128; register OLA; write A-image
// bf16 swizzled. grid 512, 256 thr.
// ---------------------------------------------------------------------------
#define MID_ROLL(J0, J1, J2, J3)                                                \
    {                                                                           \
        _Pragma("unroll") for (int e2 = 0; e2 < 2; ++e2)                        \
        _Pragma("unroll") for (int i = 0; i < 4; ++i) {                         \
            roll[e2][J0][i] = fmaf(acc[0][e2][i], win16[0][i], roll[e2][J0][i]);\
            roll[e2][J1][i] = fmaf(acc[1][e2][i], win16[1][i], roll[e2][J1][i]);\
            roll[e2][J2][i] = fmaf(acc[2][e2][i], win16[2][i], roll[e2][J2][i]);\
            roll[e2][J3][i] = fmaf(acc[3][e2][i], win16[3][i], roll[e2][J3][i]);\
        }                                                                       \
    }

#define MID_FLUSH(JJA, JJB)                                                     \
    {                                                                           \
        _Pragma("unroll") for (int i = 0; i < 4; ++i) {                         \
            int tp = 32 * (w - 1) + q * 4 + i;                                  \
            float xb = xs[tp];                                                  \
            _Pragma("unroll") for (int e2 = 0; e2 < 2; ++e2) {                  \
                float val = fmaf(roll[e2][JJA][i], renv[0][i], xb * emb2[e2]);  \
                Aimg[cbase[e2] + (size_t)tp * 16384] = f2bf(val);               \
                roll[e2][JJA][i] = 0.f;                                         \
            }                                                                   \
            int tp2 = tp + 16;                                                  \
            float xb2 = xs[tp2];                                                \
            _Pragma("unroll") for (int e2 = 0; e2 < 2; ++e2) {                  \
                float val = fmaf(roll[e2][JJB][i], renv[1][i], xb2 * emb2[e2]); \
                Aimg[cbase[e2] + (size_t)tp2 * 16384] = f2bf(val);              \
                roll[e2][JJB][i] = 0.f;                                         \
            }                                                                   \
        }                                                                       \
    }

__global__ __launch_bounds__(256) void mid_kernel(
    const float* __restrict__ x, const float* __restrict__ emb,
    const float* __restrict__ coef, const float2* __restrict__ V,
    const int* __restrict__ bins, unsigned short* __restrict__ Aimg)
{
    __shared__ unsigned short M1t[2][64 * 72];
    __shared__ unsigned short Yt[2][128 * 72];
    __shared__ float cosT[64];
    __shared__ float sinT[64];
    __shared__ float2 Vs2[19 * 32];   // rows 0 and 18 are zero halo
    __shared__ int Bns[17 * 32];
    __shared__ float xs[512];

    const int blk = blockIdx.x;
    const int b = blk >> 5, n = blk & 31;
    const int tid = threadIdx.x;
    const int wave = tid >> 6, lane = tid & 63, l15 = lane & 15, q = lane >> 4;
    const float C64 = 0.09817477042468103f;

    if (tid < 64) {
        float ang = (float)tid * C64;
        cosT[tid] = __cosf(ang);
        sinT[tid] = __sinf(ang);
    }
    {
        const float2* Vg = V + (size_t)blk * 544;
        const int* Bg = bins + (size_t)blk * 544;
        for (int i = tid; i < 544; i += 256) { Vs2[32 + i] = Vg[i]; Bns[i] = Bg[i]; }
        if (tid < 64) {
            int r = (tid < 32) ? tid : (18 * 32 + tid - 32);
            Vs2[r] = make_float2(0.f, 0.f);
        }
        for (int i = tid; i < 512; i += 256) xs[i] = x[(size_t)b * 16384 + i * 32 + n];
    }

    float win16[4][4];
    #pragma unroll
    for (int tt = 0; tt < 4; ++tt)
        #pragma unroll
        for (int i = 0; i < 4; ++i) {
            int t = tt * 16 + q * 4 + i;
            win16[tt][i] = 0.5f - 0.5f * __cosf((float)t * C64);
        }
    float renv[2][4];
    #pragma unroll
    for (int hf = 0; hf < 2; ++hf)
        #pragma unroll
        for (int i = 0; i < 4; ++i) {
            int k = hf * 16 + q * 4 + i;
            float w0 = 0.5f - 0.5f * __cosf((float)k * C64);
            float w1v = 0.5f - 0.5f * __cosf((float)(k + 32) * C64);
            renv[hf][i] = 1.0f / (w0 * w0 + w1v * w1v);
        }
    int ebase[2];
    float emb2[2];
    size_t cbase[2];
    const int mt = blk >> 7, mp = blk & 127, s = (mp >> 2) & 3;
    #pragma unroll
    for (int e2 = 0; e2 < 2; ++e2) {
        ebase[e2] = (wave * 2 + e2) * 16 + l15;
        emb2[e2] = emb[ebase[e2]];
        int e = ebase[e2];
        int echunk = e >> 5, clog = (e >> 3) & 3, cs = clog ^ s, el = e & 7;
        cbase[e2] = ((size_t)mt * 2048 + echunk) * 4096 + mp * 32 + cs * 8 + el;
    }

    float roll[2][4][4];
    #pragma unroll
    for (int e2 = 0; e2 < 2; ++e2)
        #pragma unroll
        for (int jj = 0; jj < 4; ++jj)
            #pragma unroll
            for (int i = 0; i < 4; ++i) roll[e2][jj][i] = 0.f;

    const int e1 = tid & 127;
    const int mg = (tid >> 7) << 4;
    const int tM = tid & 63;
    const int kg = wave << 4;

    __syncthreads();

    for (int w = 0; w < 17; ++w) {
        const int buf = w & 1;
        // ---- Y (bf16, packed cvt) -> Yt[buf] ----
        {
            const float4* cf = (const float4*)(coef + ((size_t)(w * 128 + e1)) * 8);
            float4 cA = cf[0];
            float4 cB = cf[1];
            unsigned int rep[8], imp[8];
            #pragma unroll
            for (int j2 = 0; j2 < 8; ++j2) {
                float rev[2], imv[2];
                #pragma unroll
                for (int sdx = 0; sdx < 2; ++sdx) {
                    int m = mg + j2 * 2 + sdx;
                    float2 vm = Vs2[(w + 1) * 32 + m];   // +1: zero-halo shift
                    float2 vl = Vs2[w * 32 + m];
                    float2 vp = Vs2[(w + 2) * 32 + m];
                    float re = cB.z;
                    re = fmaf(vm.x, cA.x, re); re = fmaf(-vm.y, cA.y, re);
                    re = fmaf(vl.x, cA.z, re); re = fmaf(-vl.y, cA.w, re);
                    re = fmaf(vp.x, cB.x, re); re = fmaf(-vp.y, cB.y, re);
                    float im = cB.w;
                    im = fmaf(vm.y, cA.x, im); im = fmaf(vm.x, cA.y, im);
                    im = fmaf(vl.y, cA.z, im); im = fmaf(vl.x, cA.w, im);
                    im = fmaf(vp.y, cB.x, im); im = fmaf(vp.x, cB.y, im);
                    rev[sdx] = fmaxf(re, 0.f);
                    imv[sdx] = fmaxf(im, 0.f);
                }
                rep[j2] = pkbf(rev[0], rev[1]);
                imp[j2] = pkbf(imv[0], imv[1]);
            }
            uint4* dr = (uint4*)&Yt[buf][e1 * 72 + mg];
            dr[0] = make_uint4(rep[0], rep[1], rep[2], rep[3]);
            dr[1] = make_uint4(rep[4], rep[5], rep[6], rep[7]);
            uint4* di = (uint4*)&Yt[buf][e1 * 72 + 32 + mg];
            di[0] = make_uint4(imp[0], imp[1], imp[2], imp[3]);
            di[1] = make_uint4(imp[4], imp[5], imp[6], imp[7]);
        }
        // ---- M1 basis (packed cvt) -> M1t[buf] ----
        {
            unsigned int mpk[8];
            #pragma unroll
            for (int j2 = 0; j2 < 8; ++j2) {
                float vv[2];
                #pragma unroll
                for (int sdx = 0; sdx < 2; ++sdx) {
                    int k = kg + j2 * 2 + sdx;
                    int m = k & 31;
                    int r = Bns[w * 32 + m];
                    float sc = (r == 0 || r == 32) ? 0.015625f : 0.03125f;
                    int idx = (r * tM) & 63;
                    vv[sdx] = (k < 32) ? (cosT[idx] * sc) : (-sinT[idx] * sc);
                }
                mpk[j2] = pkbf(vv[0], vv[1]);
            }
            uint4* dm = (uint4*)&M1t[buf][tM * 72 + kg];
            dm[0] = make_uint4(mpk[0], mpk[1], mpk[2], mpk[3]);
            dm[1] = make_uint4(mpk[4], mpk[5], mpk[6], mpk[7]);
        }
        __syncthreads();   // the only barrier this iteration

        v4f acc[4][2];
        #pragma unroll
        for (int tt = 0; tt < 4; ++tt)
            #pragma unroll
            for (int e2 = 0; e2 < 2; ++e2) acc[tt][e2] = (v4f){0.f, 0.f, 0.f, 0.f};
        #pragma unroll
        for (int ks = 0; ks < 2; ++ks) {
            v8s bfr[2];
            #pragma unroll
            for (int e2 = 0; e2 < 2; ++e2)
                bfr[e2] = *(const v8s*)&Yt[buf][ebase[e2] * 72 + ks * 32 + q * 8];
            #pragma unroll
            for (int tt = 0; tt < 4; ++tt) {
                v8s af = *(const v8s*)&M1t[buf][(tt * 16 + l15) * 72 + ks * 32 + q * 8];
                #pragma unroll
                for (int e2 = 0; e2 < 2; ++e2)
                    acc[tt][e2] = __builtin_amdgcn_mfma_f32_16x16x32_bf16(
                        af, bfr[e2], acc[tt][e2], 0, 0, 0);
            }
        }

        if ((w & 1) == 0) {
            MID_ROLL(0, 1, 2, 3);
            if (w > 0) {
                MID_FLUSH(0, 1);
            } else {
                // chunks 0,1 (abs samples [0,32)) are pad-trimmed: discard
                #pragma unroll
                for (int e2 = 0; e2 < 2; ++e2)
                    #pragma unroll
                    for (int i = 0; i < 4; ++i) {
                        roll[e2][0][i] = 0.f; roll[e2][1][i] = 0.f;
                    }
            }
        } else {
            MID_ROLL(2, 3, 0, 1);
            MID_FLUSH(2, 3);
        }
        // no trailing barrier: next iter writes buf^1; any wave writing buf^1
        // has passed barrier(w), which orders it after all iter-(w-1) reads.
    }
}

// ---------------------------------------------------------------------------
// Kernel D: FC1 split-K GEMM, 256x256 tile, 512 threads, BK=32, dbuf DMA.
// Flat grid 4*KS with XCD-pairing swizzle. Partials bf16, layout [row][ks][hid].
// ---------------------------------------------------------------------------
__global__ __launch_bounds__(512) void gemm_kernel(
    const unsigned short* __restrict__ Aimg, const unsigned short* __restrict__ w1p,
    unsigned short* __restrict__ hp, int iters, int KS)
{
    __shared__ unsigned short As[2][8192];
    __shared__ unsigned short Bs[2][8192];

    const int gid = blockIdx.x;
    const int xcd = gid & 7;
    const int u = gid >> 3;
    const int KS4 = KS >> 2;
    const int nt2 = (u >= KS4) ? 1 : 0;
    const int vv = u - nt2 * KS4;
    const int pid = vv * 8 + xcd;
    const int ks = pid >> 1;
    const int mt2 = pid & 1;

    const int tid = threadIdx.x;
    const int wave = tid >> 6, lane = tid & 63;
    const int l15 = lane & 15, q = lane >> 4;
    const int kb0 = ks * iters;

    const int isB = wave >> 2;
    const int sub = wave & 3;
    const unsigned short* gsrc = (isB
        ? w1p + ((size_t)(nt2 * 2 + (sub >> 1)) * 2048 + kb0) * 4096
        : Aimg + ((size_t)(mt2 * 2 + (sub >> 1)) * 2048 + kb0) * 4096)
        + (sub & 1) * 2048 + lane * 8;
    const int ldsoff = (sub >> 1) * 4096 + (sub & 1) * 2048;   // wave-uniform

    v4f acc[4][8];
    #pragma unroll
    for (int mf = 0; mf < 4; ++mf)
        #pragma unroll
        for (int nf = 0; nf < 8; ++nf) acc[mf][nf] = (v4f){0.f, 0.f, 0.f, 0.f};

    {
        unsigned short* dst = (isB ? Bs[0] : As[0]) + ldsoff;
        #pragma unroll
        for (int j = 0; j < 4; ++j) async16(gsrc + j * 512, dst + j * 512);
    }

    const int wm = wave >> 1, wn = wave & 1;
    const int ca = (q ^ ((l15 >> 2) & 3)) * 8;
    const int rA = (wm >> 1) * 4096 + ((wm & 1) * 64 + l15) * 32 + ca;
    const int rB = wn * 4096 + l15 * 32 + ca;

    for (int it = 0; it < iters; ++it) {
        __syncthreads();
        if (it + 1 < iters) {
            const unsigned short* src = gsrc + (size_t)(it + 1) * 4096;
            unsigned short* dst = (isB ? Bs[(it + 1) & 1] : As[(it + 1) & 1]) + ldsoff;
            #pragma unroll
            for (int j = 0; j < 4; ++j) async16(src + j * 512, dst + j * 512);
        }
        const int cur = it & 1;
        v8s af[4], bf[8];
        #pragma unroll
        for (int f = 0; f < 4; ++f) af[f] = *(const v8s*)&As[cur][rA + f * 512];
        #pragma unroll
        for (int nf = 0; nf < 8; ++nf) bf[nf] = *(const v8s*)&Bs[cur][rB + nf * 512];
        #pragma unroll
        for (int mf = 0; mf < 4; ++mf)
            #pragma unroll
            for (int nf = 0; nf < 8; ++nf)
                acc[mf][nf] = __builtin_amdgcn_mfma_f32_16x16x32_bf16(
                    af[mf], bf[nf], acc[mf][nf], 0, 0, 0);
    }

    #pragma unroll
    for (int mf = 0; mf < 4; ++mf)
        #pragma unroll
        for (int nf = 0; nf < 8; ++nf) {
            int row = mt2 * 256 + wm * 64 + mf * 16 + q * 4;
            int col = nt2 * 256 + wn * 128 + nf * 16 + l15;
            // transposed: hp[row][ks][hid] -> fc2 reads 64KB contiguous/row
            unsigned short* dst = hp + ((size_t)row * KS + ks) * 512 + col;
            #pragma unroll
            for (int i = 0; i < 4; ++i)
                dst[(size_t)i * KS * 512] = f2bf(acc[mf][nf][i]);
        }
}

// ---------------------------------------------------------------------------
// Kernel E (fused): per row — reduce bf16 split-K partials (contiguous 64KB)
// + b1 + leaky into LDS, then FC2 matvec + b2 -> out[b][p][n]. grid 512, 256 thr.
// ---------------------------------------------------------------------------
__global__ __launch_bounds__(256) void fc2_kernel(
    const unsigned short* __restrict__ hp, const float* __restrict__ b1,
    const float* __restrict__ w2, const float* __restrict__ b2,
    float* __restrict__ out, int KS)
{
    __shared__ float hbuf[512];
    const int row = blockIdx.x;
    const int tid = threadIdx.x;

    // thread t owns hids {2t, 2t+1}; hp row-major [row][ks][hid]
    const unsigned int* base = (const unsigned int*)(hp + (size_t)row * KS * 512) + tid;
    float a0 = 0.f, a1 = 0.f;
    #pragma unroll 8
    for (int k = 0; k < KS; ++k) {
        unsigned int v = base[k * 256];   // 512 ushort = 256 uint per slice
        a0 += bf2f((unsigned short)(v & 0xffff));
        a1 += bf2f((unsigned short)(v >> 16));
    }
    float s0 = a0 + b1[tid * 2];
    float s1 = a1 + b1[tid * 2 + 1];
    hbuf[tid * 2]     = (s0 > 0.f) ? s0 : 0.01f * s0;
    hbuf[tid * 2 + 1] = (s1 > 0.f) ? s1 : 0.01f * s1;
    __syncthreads();

    if (tid < 96) {
        float a = b2[tid];
        #pragma unroll 8
        for (int h = 0; h < 512; ++h) a = fmaf(hbuf[h], w2[h * 96 + tid], a);
        int b = row >> 5, n = row & 31;
        out[(size_t)b * 3072 + tid * 32 + n] = a;
    }
}

// ---------------------------------------------------------------------------
extern "C" void kernel_launch(void* const* d_in, const int* in_sizes, int n_in,
                              void* d_out, int out_size, void* d_ws, size_t ws_size,
                              hipStream_t stream) {
    const float* x   = (const float*)d_in[0];
    const float* emb = (const float*)d_in[1];
    const float* Wr  = (const float*)d_in[2];
    const float* Wi  = (const float*)d_in[3];
    const float* Wrl = (const float*)d_in[4];
    const float* Wil = (const float*)d_in[5];
    const float* Wrr = (const float*)d_in[6];
    const float* Wir = (const float*)d_in[7];
    const float* br  = (const float*)d_in[8];
    const float* bi  = (const float*)d_in[9];
    const float* w1  = (const float*)d_in[10];
    const float* b1  = (const float*)d_in[11];
    const float* w2  = (const float*)d_in[12];
    const float* b2  = (const float*)d_in[13];

    char* ws = (char*)d_ws;
    float* coef          = (float*)(ws + OFF_COEF);
    float2* V            = (float2*)(ws + OFF_V);
    int* bins            = (int*)(ws + OFF_BINS);
    unsigned short* Aimg = (unsigned short*)(ws + OFF_AIMG);
    unsigned short* w1p  = (unsigned short*)(ws + OFF_W1P);
    unsigned short* hpp  = (unsigned short*)(ws + OFF_HP);

    int KS = 64;
    size_t hp_bytes = (size_t)KS * 512 * 512 * 2;
    if (OFF_HP + hp_bytes > ws_size) {
        KS = 32; hp_bytes = (size_t)KS * 512 * 512 * 2;
    }
    int iters = 2048 / KS;

    coef_kernel<<<dim3(17, 8), dim3(128), 0, stream>>>(
        emb, Wr, Wi, Wrl, Wil, Wrr, Wir, br, bi, coef);
    cvt_kernel<<<dim3(2048, 4), dim3(256), 0, stream>>>(w1, w1p);
    stft_kernel<<<dim3(512), dim3(256), 0, stream>>>(x, V, bins);
    mid_kernel<<<dim3(512), dim3(256), 0, stream>>>(x, emb, coef, V, bins, Aimg);
    gemm_kernel<<<dim3(4 * KS), dim3(512), 0, stream>>>(Aimg, w1p, hpp, iters, KS);
    fc2_kernel<<<dim3(512), dim3(256), 0, stream>>>(hpp, b1, w2, b2, (float*)d_out, KS);
}